// Round 1
// baseline (5854.524 us; speedup 1.0000x reference)
//
#include <hip/hip_runtime.h>
#include <math.h>

// Problem constants
#define T_STEPS 256
#define BATCH   256
#define HID     512
#define DIN     640     // P*F = 5*128
#define NCOL    2048    // 4*H
#define NCLASS  60
#define KSTEPS  36      // 1152 / 32  (20 x-part + 16 h-part)

typedef float f32x4 __attribute__((ext_vector_type(4)));
typedef short s16x8 __attribute__((ext_vector_type(8)));

__device__ __forceinline__ unsigned short f2bf(float x) {
    union { float f; unsigned u; } v; v.f = x;
    unsigned r = v.u + 0x7fffu + ((v.u >> 16) & 1u);   // round-to-nearest-even
    return (unsigned short)(r >> 16);
}

__device__ __forceinline__ s16x8 pack8(float4 a, float4 b) {
    s16x8 r;
    r[0] = (short)f2bf(a.x); r[1] = (short)f2bf(a.y);
    r[2] = (short)f2bf(a.z); r[3] = (short)f2bf(a.w);
    r[4] = (short)f2bf(b.x); r[5] = (short)f2bf(b.y);
    r[6] = (short)f2bf(b.z); r[7] = (short)f2bf(b.w);
    return r;
}

// ---------------------------------------------------------------------------
// Pack [Wx; Wh] (1152 x 2048 fp32) into bf16 B-fragment-linear layout:
//   Wf[nb][ks][lane][8], nb = hg*4 + gate  (hg in [0,32), gate in {i,f,g,o})
//   col n = gate*512 + hg*16 + (lane&15);  k = ks*32 + (lane>>4)*8 + j
// One thread produces one lane's 8 bf16 (16B coalesced store).
// ---------------------------------------------------------------------------
__global__ __launch_bounds__(256) void pack_w_kernel(
    const float* __restrict__ Wx, const float* __restrict__ Wh,
    unsigned short* __restrict__ Wf)
{
    int g = blockIdx.x * 256 + threadIdx.x;      // [0, 128*36*64)
    int nb  = g / (KSTEPS * 64);
    int rem = g - nb * (KSTEPS * 64);
    int ks = rem >> 6;
    int lane = rem & 63;
    int gate = nb & 3, hg = nb >> 2;
    int n = gate * 512 + hg * 16 + (lane & 15);
    int kbase = ks * 32 + (lane >> 4) * 8;
    s16x8 frag;
    #pragma unroll
    for (int j = 0; j < 8; j++) {
        int k = kbase + j;
        float v = (k < DIN) ? Wx[(size_t)k * NCOL + n]
                            : Wh[(size_t)(k - DIN) * NCOL + n];
        frag[j] = (short)f2bf(v);
    }
    *(s16x8*)(Wf + (size_t)g * 8) = frag;
}

// ---------------------------------------------------------------------------
// One recurrence step. Grid: 128 WGs = 4 m-tiles (64 batch) x 32 hidden-groups
// (16 hidden units = 64 gate cols). 4 waves: wm = m-half (32 rows), wn = gate
// pair. Each wave: 2 m-blocks x 2 n-blocks of mfma_f32_16x16x32_bf16.
// h state: hsrc/hdst are bf16 A-frag-linear [mb(16)][khs(16)][lane][8].
// ---------------------------------------------------------------------------
__global__ __launch_bounds__(256) void step_kernel(
    const float* __restrict__ x,              // (B,5,T,128) fp32
    const unsigned short* __restrict__ Wf,    // packed weights
    const unsigned short* __restrict__ hsrc,  // prev h, frag layout
    unsigned short* __restrict__ hdst,        // next h, frag layout
    float* __restrict__ cbuf,                 // (B,512) fp32 cell state
    float* __restrict__ hplain,               // (B,512) fp32 h state
    const float* __restrict__ bias,           // 2048
    const float* __restrict__ tau,            // 512
    const float* __restrict__ shift,          // 512
    int t)
{
    __shared__ float gl[64][64];              // gates tile, 64KB
    int tid = threadIdx.x;
    int lane = tid & 63, w = tid >> 6;
    int wm = w & 1, wn = w >> 1;
    int mt = blockIdx.x >> 5, hg = blockIdx.x & 31;
    int quad = lane >> 4, l16 = lane & 15;
    int r0 = mt * 64 + wm * 32 + l16;
    int r1 = r0 + 16;
    int mb0 = mt * 4 + wm * 2;

    f32x4 acc00 = {0.f, 0.f, 0.f, 0.f};
    f32x4 acc01 = acc00, acc10 = acc00, acc11 = acc00;

    const unsigned short* wf0 = Wf + (((size_t)(hg * 4 + wn * 2) * KSTEPS) * 64 + lane) * 8;
    const unsigned short* wf1 = wf0 + (size_t)KSTEPS * 64 * 8;

    // --- x part: ksteps 0..19 (K = 640), convert fp32 -> bf16 on the fly ---
    #pragma unroll 4
    for (int ks = 0; ks < 20; ks++) {
        int k = ks * 32 + quad * 8;
        int p = k >> 7, f = k & 127;
        const float* s0 = x + ((size_t)(r0 * 5 + p) * 256 + t) * 128 + f;
        const float* s1 = x + ((size_t)(r1 * 5 + p) * 256 + t) * 128 + f;
        float4 u0 = *(const float4*)s0;
        float4 u1 = *(const float4*)(s0 + 4);
        float4 v0 = *(const float4*)s1;
        float4 v1 = *(const float4*)(s1 + 4);
        s16x8 a0 = pack8(u0, u1);
        s16x8 a1 = pack8(v0, v1);
        s16x8 b0 = *(const s16x8*)(wf0 + (size_t)ks * 64 * 8);
        s16x8 b1 = *(const s16x8*)(wf1 + (size_t)ks * 64 * 8);
        acc00 = __builtin_amdgcn_mfma_f32_16x16x32_bf16(a0, b0, acc00, 0, 0, 0);
        acc10 = __builtin_amdgcn_mfma_f32_16x16x32_bf16(a1, b0, acc10, 0, 0, 0);
        acc01 = __builtin_amdgcn_mfma_f32_16x16x32_bf16(a0, b1, acc01, 0, 0, 0);
        acc11 = __builtin_amdgcn_mfma_f32_16x16x32_bf16(a1, b1, acc11, 0, 0, 0);
    }
    // --- h part: ksteps 20..35 (K = 512), bf16 frags straight from global ---
    #pragma unroll 4
    for (int khs = 0; khs < 16; khs++) {
        s16x8 a0 = *(const s16x8*)(hsrc + (((size_t)mb0 * 16 + khs) * 64 + lane) * 8);
        s16x8 a1 = *(const s16x8*)(hsrc + (((size_t)(mb0 + 1) * 16 + khs) * 64 + lane) * 8);
        int ks = 20 + khs;
        s16x8 b0 = *(const s16x8*)(wf0 + (size_t)ks * 64 * 8);
        s16x8 b1 = *(const s16x8*)(wf1 + (size_t)ks * 64 * 8);
        acc00 = __builtin_amdgcn_mfma_f32_16x16x32_bf16(a0, b0, acc00, 0, 0, 0);
        acc10 = __builtin_amdgcn_mfma_f32_16x16x32_bf16(a1, b0, acc10, 0, 0, 0);
        acc01 = __builtin_amdgcn_mfma_f32_16x16x32_bf16(a0, b1, acc01, 0, 0, 0);
        acc11 = __builtin_amdgcn_mfma_f32_16x16x32_bf16(a1, b1, acc11, 0, 0, 0);
    }

    // --- dump accumulators to LDS (C/D layout: col=lane&15, row=quad*4+reg) ---
    int colb = (wn * 2) * 16 + l16;
    int rowb = wm * 32 + quad * 4;
    #pragma unroll
    for (int r = 0; r < 4; r++) {
        gl[rowb + r][colb]           = acc00[r];
        gl[rowb + r][colb + 16]      = acc01[r];
        gl[rowb + 16 + r][colb]      = acc10[r];
        gl[rowb + 16 + r][colb + 16] = acc11[r];
    }
    __syncthreads();

    // --- epilogue: bias + activations + cell + phased time gate (fp32) ---
    #pragma unroll
    for (int rep = 0; rep < 4; rep++) {
        int idx = rep * 256 + tid;
        int b_l = idx >> 4, j_l = idx & 15;
        int bG = mt * 64 + b_l, jG = hg * 16 + j_l;
        float iv = gl[b_l][j_l]       + bias[jG];
        float fv = gl[b_l][16 + j_l]  + bias[512 + jG];
        float gv = gl[b_l][32 + j_l]  + bias[1024 + jG];
        float ov = gl[b_l][48 + j_l]  + bias[1536 + jG];
        iv = 1.f / (1.f + expf(-iv));
        fv = 1.f / (1.f + expf(-fv));
        gv = tanhf(gv);
        ov = 1.f / (1.f + expf(-ov));
        size_t ci = (size_t)bG * HID + jG;
        float c_old = cbuf[ci], h_old = hplain[ci];
        float ct = fv * c_old + iv * gv;
        float ht = ov * tanhf(ct);
        float tj = tau[jG], sj = shift[jG];
        float phi = fmodf((float)t - sj, tj);
        phi = (phi < 0.f) ? phi + tj : phi;     // jnp.mod semantics (tau > 0)
        phi /= tj;
        float kg = (phi < 0.025f) ? 40.f * phi
                 : ((phi < 0.05f) ? 2.f - 40.f * phi : 0.001f * phi);
        float cn = kg * ct + (1.f - kg) * c_old;
        float hn = kg * ht + (1.f - kg) * h_old;
        cbuf[ci] = cn;
        hplain[ci] = hn;
        // write bf16 h into A-frag layout for next step's MFMA
        int mb = bG >> 4, khs2 = jG >> 5;
        int ln = (bG & 15) + ((jG >> 3) & 3) * 16;
        hdst[(((size_t)mb * 16 + khs2) * 64 + ln) * 8 + (jG & 7)] = f2bf(hn);
    }
}

// ---------------------------------------------------------------------------
// Final FC (512 -> 60) + log_softmax. One wave per batch row.
// ---------------------------------------------------------------------------
__global__ __launch_bounds__(64) void fc_kernel(
    const float* __restrict__ hplain, const float* __restrict__ fcw,
    const float* __restrict__ fcb, float* __restrict__ out)
{
    int b = blockIdx.x, lane = threadIdx.x;
    float logit = -INFINITY;
    if (lane < NCLASS) {
        float s = fcb[lane];
        const float* hp = hplain + (size_t)b * HID;
        #pragma unroll 8
        for (int k = 0; k < HID; k++)
            s += hp[k] * fcw[(size_t)k * NCLASS + lane];
        logit = s;
    }
    float m = logit;
    for (int off = 32; off > 0; off >>= 1)
        m = fmaxf(m, __shfl_xor(m, off, 64));
    float e = (lane < NCLASS) ? expf(logit - m) : 0.f;
    float se = e;
    for (int off = 32; off > 0; off >>= 1)
        se += __shfl_xor(se, off, 64);
    if (lane < NCLASS)
        out[(size_t)b * NCLASS + lane] = logit - m - logf(se);
}

// ---------------------------------------------------------------------------
// ws layout (bytes):
//   [0,        4718592)  Wf      bf16 packed weights (128*36*64*8)
//   [4718592,  4980736)  hfrag0  bf16 h frag buffer
//   [4980736,  5242880)  hfrag1  bf16 h frag buffer
//   [5242880,  5767168)  cbuf    fp32 (256x512)
//   [5767168,  6291456)  hplain  fp32 (256x512)
// ---------------------------------------------------------------------------
extern "C" void kernel_launch(void* const* d_in, const int* in_sizes, int n_in,
                              void* d_out, int out_size, void* d_ws, size_t ws_size,
                              hipStream_t stream)
{
    const float* x     = (const float*)d_in[0];
    const float* Wx    = (const float*)d_in[1];
    const float* Wh    = (const float*)d_in[2];
    const float* bias  = (const float*)d_in[3];
    const float* tau   = (const float*)d_in[4];
    const float* shift = (const float*)d_in[5];
    const float* fcw   = (const float*)d_in[6];
    const float* fcb   = (const float*)d_in[7];
    float* out = (float*)d_out;
    char* ws = (char*)d_ws;

    unsigned short* Wf  = (unsigned short*)(ws);
    unsigned short* hf0 = (unsigned short*)(ws + 4718592);
    unsigned short* hf1 = (unsigned short*)(ws + 4980736);
    float* cbuf   = (float*)(ws + 5242880);
    float* hplain = (float*)(ws + 5767168);

    // zero h-frag ping-pong buffers, c, and h (initial state = 0)
    hipMemsetAsync(ws + 4718592, 0, 6291456 - 4718592, stream);

    pack_w_kernel<<<dim3(1152), dim3(256), 0, stream>>>(Wx, Wh, Wf);

    for (int t = 0; t < T_STEPS; t++) {
        const unsigned short* hs = (t & 1) ? hf1 : hf0;
        unsigned short*       hd = (t & 1) ? hf0 : hf1;
        step_kernel<<<dim3(128), dim3(256), 0, stream>>>(
            x, Wf, hs, hd, cbuf, hplain, bias, tau, shift, t);
    }

    fc_kernel<<<dim3(256), dim3(64), 0, stream>>>(hplain, fcw, fcb, out);
}

// Round 2
// 5702.876 us; speedup vs baseline: 1.0266x; 1.0266x over previous
//
#include <hip/hip_runtime.h>
#include <math.h>

// Problem constants
#define T_STEPS 256
#define BATCH   256
#define HID     512
#define DIN     640     // P*F = 5*128
#define NCOL    2048    // 4*H
#define NCLASS  60
#define KSTEPS  36      // 1152 / 32
#define KX      20      // x-part k-steps (640/32)
#define KH      16      // h-part k-steps (512/32)

typedef float f32x4 __attribute__((ext_vector_type(4)));
typedef short s16x8 __attribute__((ext_vector_type(8)));

// ws layout (bytes):
//   [0,       1024)     barrier counters (8 groups, 128 B apart)
//   [1024,    4719616)  Wf  bf16 packed weights (128*36*64*8 shorts)
//   [4719616, 4981760)  hb0 bf16 h frag buffer
//   [4981760, 5243904)  hb1 bf16 h frag buffer
//   [5243904, 5768192)  hplain fp32 (256x512)
#define WF_OFF   1024
#define HB0_OFF  4719616
#define HB1_OFF  4981760
#define HPL_OFF  5243904

__device__ __forceinline__ unsigned short f2bf(float x) {
    union { float f; unsigned u; } v; v.f = x;
    unsigned r = v.u + 0x7fffu + ((v.u >> 16) & 1u);   // round-to-nearest-even
    return (unsigned short)(r >> 16);
}

__device__ __forceinline__ s16x8 pack8(float4 a, float4 b) {
    s16x8 r;
    r[0] = (short)f2bf(a.x); r[1] = (short)f2bf(a.y);
    r[2] = (short)f2bf(a.z); r[3] = (short)f2bf(a.w);
    r[4] = (short)f2bf(b.x); r[5] = (short)f2bf(b.y);
    r[6] = (short)f2bf(b.z); r[7] = (short)f2bf(b.w);
    return r;
}

// ---------------------------------------------------------------------------
// Pack [Wx; Wh] (1152 x 2048 fp32) into bf16 B-fragment-linear layout:
//   Wf[nb][ks][lane][8], nb = hg*4 + gate; col n = gate*512 + hg*16 + (lane&15)
//   k = ks*32 + (lane>>4)*8 + j
// ---------------------------------------------------------------------------
__global__ __launch_bounds__(256) void pack_w_kernel(
    const float* __restrict__ Wx, const float* __restrict__ Wh,
    unsigned short* __restrict__ Wf)
{
    int g = blockIdx.x * 256 + threadIdx.x;      // [0, 128*36*64)
    int nb  = g / (KSTEPS * 64);
    int rem = g - nb * (KSTEPS * 64);
    int ks = rem >> 6;
    int lane = rem & 63;
    int gate = nb & 3, hg = nb >> 2;
    int n = gate * 512 + hg * 16 + (lane & 15);
    int kbase = ks * 32 + (lane >> 4) * 8;
    s16x8 frag;
    #pragma unroll
    for (int j = 0; j < 8; j++) {
        int k = kbase + j;
        float v = (k < DIN) ? Wx[(size_t)k * NCOL + n]
                            : Wh[(size_t)(k - DIN) * NCOL + n];
        frag[j] = (short)f2bf(v);
    }
    *(s16x8*)(Wf + (size_t)g * 8) = frag;
}

// ---------------------------------------------------------------------------
// Persistent phased-LSTM kernel. 256 WGs x 256 threads, 1 WG/CU (LDS-bound).
// WG = (mt = bid&7, hg = bid>>3): 32 batch rows x 64 gate cols (16 hidden).
// Weights slice lives in LDS; c,h state lives in registers (2 cells/thread);
// h exchanged between WGs of the same mt-group via global bf16 frag ping-pong
// with an 8-way-independent 32-WG atomic barrier + agent-scope fences.
// ---------------------------------------------------------------------------
__global__ __launch_bounds__(256, 1) void plstm_persist(
    const float* __restrict__ x,              // (B,5,T,128) fp32
    const unsigned short* __restrict__ Wf,    // packed weights (global)
    unsigned short* __restrict__ hb0,         // h frag ping
    unsigned short* __restrict__ hb1,         // h frag pong
    float* __restrict__ hplain,               // final h (B,512) fp32
    const float* __restrict__ bias,
    const float* __restrict__ tau,
    const float* __restrict__ shift,
    int* __restrict__ cnt)                    // 8 counters, 32-int stride
{
    __shared__ unsigned short wfl[4 * KSTEPS * 64 * 8];  // 147456 B
    __shared__ float gl[32][64];                          // 8192 B

    int tid = threadIdx.x;
    int lane = tid & 63, w = tid >> 6;
    int mt = blockIdx.x & 7, hg = blockIdx.x >> 3;
    int quad = lane >> 4, l16 = lane & 15;
    int mb = w & 1;                 // which 16-row block of this WG
    int n0 = (w >> 1) * 2;          // first of this wave's 2 col-blocks (0 or 2)

    // --- stage weight slice into LDS (linear, coalesced) ---
    {
        const s16x8* src = (const s16x8*)(Wf + (size_t)(hg * 4) * KSTEPS * 64 * 8);
        s16x8* dst = (s16x8*)wfl;
        #pragma unroll
        for (int i = 0; i < 36; i++)
            dst[i * 256 + tid] = src[i * 256 + tid];
    }

    // --- per-thread epilogue constants + register-resident c,h (2 cells) ---
    float creg[2] = {0.f, 0.f}, hreg[2] = {0.f, 0.f};
    float bi[2], bff[2], bg[2], bo[2], tj[2], sj[2];
    int bGc[2], jGc[2];
    #pragma unroll
    for (int r = 0; r < 2; r++) {
        int idx = r * 256 + tid;
        int b_l = idx >> 4, j_l = idx & 15;
        int jG = hg * 16 + j_l;
        bGc[r] = mt * 32 + b_l; jGc[r] = jG;
        bi[r] = bias[jG];        bff[r] = bias[512 + jG];
        bg[r] = bias[1024 + jG]; bo[r] = bias[1536 + jG];
        tj[r] = tau[jG];         sj[r] = shift[jG];
    }
    __syncthreads();

    int rowA = mt * 32 + mb * 16 + l16;   // this lane's A-operand batch row
    int mbg  = mt * 2 + mb;               // global 16-row block index
    int* mycnt = cnt + mt * 32;           // group counter (128 B apart)

    for (int t = 0; t < T_STEPS; t++) {
        // ---- x fragments: no h dependence, issue BEFORE barrier spin ----
        s16x8 xf[KX];
        #pragma unroll
        for (int ks = 0; ks < KX; ks++) {
            int k = ks * 32 + quad * 8;
            int p = k >> 7, f = k & 127;
            const float* sp = x + ((size_t)(rowA * 5 + p) * 256 + t) * 128 + f;
            float4 u0 = *(const float4*)sp;
            float4 u1 = *(const float4*)(sp + 4);
            xf[ks] = pack8(u0, u1);
        }

        // ---- group barrier: wait for all 32 WGs of mt to finish step t-1 ----
        if (tid == 0) {
            while (__hip_atomic_load(mycnt, __ATOMIC_ACQUIRE,
                                     __HIP_MEMORY_SCOPE_AGENT) < 32 * t)
                __builtin_amdgcn_s_sleep(1);
            __threadfence();   // acquire: invalidate L1/L2 so h reads are fresh
        }
        __syncthreads();

        const unsigned short* hsrc = (t & 1) ? hb1 : hb0;
        unsigned short*       hdst = (t & 1) ? hb0 : hb1;

        // ---- h fragments (fresh after barrier) ----
        s16x8 hf[KH];
        #pragma unroll
        for (int khs = 0; khs < KH; khs++)
            hf[khs] = *(const s16x8*)(hsrc + (((size_t)mbg * KH + khs) * 64 + lane) * 8);

        // ---- MFMA: K = 640 (x) + 512 (h), B from LDS ----
        f32x4 acc0 = {0.f, 0.f, 0.f, 0.f}, acc1 = acc0;
        #pragma unroll
        for (int ks = 0; ks < KX; ks++) {
            s16x8 b0 = *(const s16x8*)(wfl + (((n0    ) * KSTEPS + ks) * 64 + lane) * 8);
            s16x8 b1 = *(const s16x8*)(wfl + (((n0 + 1) * KSTEPS + ks) * 64 + lane) * 8);
            acc0 = __builtin_amdgcn_mfma_f32_16x16x32_bf16(xf[ks], b0, acc0, 0, 0, 0);
            acc1 = __builtin_amdgcn_mfma_f32_16x16x32_bf16(xf[ks], b1, acc1, 0, 0, 0);
        }
        #pragma unroll
        for (int khs = 0; khs < KH; khs++) {
            int ks = KX + khs;
            s16x8 b0 = *(const s16x8*)(wfl + (((n0    ) * KSTEPS + ks) * 64 + lane) * 8);
            s16x8 b1 = *(const s16x8*)(wfl + (((n0 + 1) * KSTEPS + ks) * 64 + lane) * 8);
            acc0 = __builtin_amdgcn_mfma_f32_16x16x32_bf16(hf[khs], b0, acc0, 0, 0, 0);
            acc1 = __builtin_amdgcn_mfma_f32_16x16x32_bf16(hf[khs], b1, acc1, 0, 0, 0);
        }

        // ---- dump accs to LDS (C/D layout: col=lane&15, row=quad*4+reg) ----
        int colb = n0 * 16 + l16;
        int rowb = mb * 16 + quad * 4;
        #pragma unroll
        for (int r = 0; r < 4; r++) {
            gl[rowb + r][colb]      = acc0[r];
            gl[rowb + r][colb + 16] = acc1[r];
        }
        __syncthreads();

        // ---- epilogue: activations + cell + phased gate, state in regs ----
        #pragma unroll
        for (int r = 0; r < 2; r++) {
            int idx = r * 256 + tid;
            int b_l = idx >> 4, j_l = idx & 15;
            float iv = gl[b_l][j_l]      + bi[r];
            float fv = gl[b_l][16 + j_l] + bff[r];
            float gv = gl[b_l][32 + j_l] + bg[r];
            float ov = gl[b_l][48 + j_l] + bo[r];
            iv = 1.f / (1.f + expf(-iv));
            fv = 1.f / (1.f + expf(-fv));
            gv = tanhf(gv);
            ov = 1.f / (1.f + expf(-ov));
            float ct = fv * creg[r] + iv * gv;
            float ht = ov * tanhf(ct);
            float phi = fmodf((float)t - sj[r], tj[r]);
            phi = (phi < 0.f) ? phi + tj[r] : phi;
            phi /= tj[r];
            float kg = (phi < 0.025f) ? 40.f * phi
                     : ((phi < 0.05f) ? 2.f - 40.f * phi : 0.001f * phi);
            creg[r] = kg * ct + (1.f - kg) * creg[r];
            hreg[r] = kg * ht + (1.f - kg) * hreg[r];
            // publish h as bf16 A-frag for next step
            int bG = bGc[r], jG = jGc[r];
            int mb2 = bG >> 4, khs2 = jG >> 5;
            int ln = (bG & 15) + ((jG >> 3) & 3) * 16;
            hdst[(((size_t)mb2 * KH + khs2) * 64 + ln) * 8 + (jG & 7)] = f2bf(hreg[r]);
            if (t == T_STEPS - 1)
                hplain[(size_t)bG * HID + jG] = hreg[r];
        }
        __syncthreads();   // all h stores issued+drained; gl safe to reuse

        // ---- group barrier arrive (release) ----
        if (tid == 0) {
            __threadfence();   // flush XCD L2 so h is visible device-wide
            __hip_atomic_fetch_add(mycnt, 1, __ATOMIC_RELEASE,
                                   __HIP_MEMORY_SCOPE_AGENT);
        }
    }
}

// ---------------------------------------------------------------------------
// Final FC (512 -> 60) + log_softmax. One wave per batch row.
// ---------------------------------------------------------------------------
__global__ __launch_bounds__(64) void fc_kernel(
    const float* __restrict__ hplain, const float* __restrict__ fcw,
    const float* __restrict__ fcb, float* __restrict__ out)
{
    int b = blockIdx.x, lane = threadIdx.x;
    float logit = -INFINITY;
    if (lane < NCLASS) {
        float s = fcb[lane];
        const float* hp = hplain + (size_t)b * HID;
        #pragma unroll 8
        for (int k = 0; k < HID; k++)
            s += hp[k] * fcw[(size_t)k * NCLASS + lane];
        logit = s;
    }
    float m = logit;
    for (int off = 32; off > 0; off >>= 1)
        m = fmaxf(m, __shfl_xor(m, off, 64));
    float e = (lane < NCLASS) ? expf(logit - m) : 0.f;
    float se = e;
    for (int off = 32; off > 0; off >>= 1)
        se += __shfl_xor(se, off, 64);
    if (lane < NCLASS)
        out[(size_t)b * NCLASS + lane] = logit - m - logf(se);
}

extern "C" void kernel_launch(void* const* d_in, const int* in_sizes, int n_in,
                              void* d_out, int out_size, void* d_ws, size_t ws_size,
                              hipStream_t stream)
{
    const float* x     = (const float*)d_in[0];
    const float* Wx    = (const float*)d_in[1];
    const float* Wh    = (const float*)d_in[2];
    const float* bias  = (const float*)d_in[3];
    const float* tau   = (const float*)d_in[4];
    const float* shift = (const float*)d_in[5];
    const float* fcw   = (const float*)d_in[6];
    const float* fcb   = (const float*)d_in[7];
    float* out = (float*)d_out;
    char* ws = (char*)d_ws;

    int*            cntp   = (int*)ws;
    unsigned short* Wf     = (unsigned short*)(ws + WF_OFF);
    unsigned short* hb0    = (unsigned short*)(ws + HB0_OFF);
    unsigned short* hb1    = (unsigned short*)(ws + HB1_OFF);
    float*          hplain = (float*)(ws + HPL_OFF);

    hipMemsetAsync(ws, 0, 1024, stream);                     // counters
    hipMemsetAsync(ws + HB0_OFF, 0, 262144, stream);         // h0 = 0

    pack_w_kernel<<<dim3(1152), dim3(256), 0, stream>>>(Wx, Wh, Wf);

    plstm_persist<<<dim3(256), dim3(256), 0, stream>>>(
        x, Wf, hb0, hb1, hplain, bias, tau, shift, cntp);

    fc_kernel<<<dim3(256), dim3(64), 0, stream>>>(hplain, fcw, fcb, out);
}

// Round 3
// 2816.689 us; speedup vs baseline: 2.0785x; 2.0247x over previous
//
#include <hip/hip_runtime.h>
#include <math.h>

// Problem constants
#define T_STEPS 256
#define BATCH   256
#define HID     512
#define DIN     640     // P*F = 5*128
#define NCOL    2048    // 4*H
#define NCLASS  60
#define KSTEPS  36      // 1152 / 32
#define KX      20      // x-part k-steps (640/32)
#define KH      16      // h-part k-steps (512/32)

typedef float f32x4 __attribute__((ext_vector_type(4)));
typedef short s16x8 __attribute__((ext_vector_type(8)));

// ws layout (bytes):
//   [0,       1024)     barrier counters (8 groups, 128 B apart)
//   [1024,    4719616)  Wf  bf16 packed weights (128*36*64*8 shorts)
//   [4719616, 4981760)  hb0 bf16 h frag buffer
//   [4981760, 5243904)  hb1 bf16 h frag buffer
//   [5243904, 5768192)  hplain fp32 (256x512)
#define WF_OFF   1024
#define HB0_OFF  4719616
#define HB1_OFF  4981760
#define HPL_OFF  5243904

__device__ __forceinline__ unsigned short f2bf(float x) {
    union { float f; unsigned u; } v; v.f = x;
    unsigned r = v.u + 0x7fffu + ((v.u >> 16) & 1u);   // round-to-nearest-even
    return (unsigned short)(r >> 16);
}

__device__ __forceinline__ s16x8 pack8(float4 a, float4 b) {
    s16x8 r;
    r[0] = (short)f2bf(a.x); r[1] = (short)f2bf(a.y);
    r[2] = (short)f2bf(a.z); r[3] = (short)f2bf(a.w);
    r[4] = (short)f2bf(b.x); r[5] = (short)f2bf(b.y);
    r[6] = (short)f2bf(b.z); r[7] = (short)f2bf(b.w);
    return r;
}

// ---------------------------------------------------------------------------
// Pack [Wx; Wh] (1152 x 2048 fp32) into bf16 B-fragment-linear layout:
//   Wf[nb][ks][lane][8], nb = hg*4 + gate; col n = gate*512 + hg*16 + (lane&15)
//   k = ks*32 + (lane>>4)*8 + j
// ---------------------------------------------------------------------------
__global__ __launch_bounds__(256) void pack_w_kernel(
    const float* __restrict__ Wx, const float* __restrict__ Wh,
    unsigned short* __restrict__ Wf)
{
    int g = blockIdx.x * 256 + threadIdx.x;      // [0, 128*36*64)
    int nb  = g / (KSTEPS * 64);
    int rem = g - nb * (KSTEPS * 64);
    int ks = rem >> 6;
    int lane = rem & 63;
    int gate = nb & 3, hg = nb >> 2;
    int n = gate * 512 + hg * 16 + (lane & 15);
    int kbase = ks * 32 + (lane >> 4) * 8;
    s16x8 frag;
    #pragma unroll
    for (int j = 0; j < 8; j++) {
        int k = kbase + j;
        float v = (k < DIN) ? Wx[(size_t)k * NCOL + n]
                            : Wh[(size_t)(k - DIN) * NCOL + n];
        frag[j] = (short)f2bf(v);
    }
    *(s16x8*)(Wf + (size_t)g * 8) = frag;
}

// ---------------------------------------------------------------------------
// Persistent phased-LSTM kernel. 256 WGs x 256 threads, 1 WG/CU (LDS-bound).
// WG = (mt = bid&7, hg = bid>>3): 32 batch rows x 64 gate cols (16 hidden).
// Cross-WG h exchange + barrier counters use relaxed agent-scope atomics
// ONLY (sc0/sc1 per-access coherence at LLC) — no threadfence, so no
// buffer_wbl2 / buffer_inv cache-maintenance in the hot loop.
// x-part MFMAs run BEFORE the barrier spin (independent of h).
// ---------------------------------------------------------------------------
__global__ __launch_bounds__(256, 1) void plstm_persist(
    const float* __restrict__ x,              // (B,5,T,128) fp32
    const unsigned short* __restrict__ Wf,    // packed weights (global)
    unsigned short* __restrict__ hb0,         // h frag ping
    unsigned short* __restrict__ hb1,         // h frag pong
    float* __restrict__ hplain,               // final h (B,512) fp32
    const float* __restrict__ bias,
    const float* __restrict__ tau,
    const float* __restrict__ shift,
    int* __restrict__ cnt)                    // 8 counters, 32-int stride
{
    __shared__ unsigned short wfl[4 * KSTEPS * 64 * 8];  // 147456 B
    __shared__ float gl[32][65];                          // padded: no 4-way conflicts

    int tid = threadIdx.x;
    int lane = tid & 63, w = tid >> 6;
    int mt = blockIdx.x & 7, hg = blockIdx.x >> 3;
    int quad = lane >> 4, l16 = lane & 15;
    int mb = w & 1;                 // which 16-row block of this WG
    int n0 = (w >> 1) * 2;          // first of this wave's 2 col-blocks (0 or 2)

    // --- stage weight slice into LDS (linear, coalesced) ---
    {
        const s16x8* src = (const s16x8*)(Wf + (size_t)(hg * 4) * KSTEPS * 64 * 8);
        s16x8* dst = (s16x8*)wfl;
        #pragma unroll
        for (int i = 0; i < 36; i++)
            dst[i * 256 + tid] = src[i * 256 + tid];
    }

    // --- per-thread epilogue constants + register-resident c,h -----------
    // epilogue thread mapping: b_l = tid>>3 (32 rows), j_l = (tid&7)*2 (+1)
    // -> 2 adjacent hidden units per thread -> ONE u32 atomic publish store.
    int b_l  = tid >> 3;
    int j_l0 = (tid & 7) * 2;
    int bG   = mt * 32 + b_l;
    int jG0  = hg * 16 + j_l0;          // even; jG1 = jG0+1
    float bi[2], bff[2], bg[2], bo[2], tj[2], sj[2];
    #pragma unroll
    for (int r = 0; r < 2; r++) {
        int jG = jG0 + r;
        bi[r] = bias[jG];        bff[r] = bias[512 + jG];
        bg[r] = bias[1024 + jG]; bo[r] = bias[1536 + jG];
        tj[r] = tau[jG];         sj[r] = shift[jG];
    }
    float creg[2] = {0.f, 0.f}, hreg[2] = {0.f, 0.f};
    // u32 index of this thread's h publish slot (pair of adjacent bf16):
    //   short idx S = ((mb2*16 + khs2)*64 + ln)*8 + (jG&7); pair -> S/2
    size_t pub32;
    {
        int mb2  = bG >> 4, khs2 = jG0 >> 5;
        int ln   = (bG & 15) + ((jG0 >> 3) & 3) * 16;
        pub32 = ((((size_t)mb2 * KH + khs2) * 64 + ln) * 8 + (jG0 & 7)) >> 1;
    }
    __syncthreads();

    int rowA = mt * 32 + mb * 16 + l16;   // this lane's A-operand batch row
    int mbg  = mt * 2 + mb;               // global 16-row block index
    int* mycnt = cnt + mt * 32;           // group counter (128 B apart)

    for (int t = 0; t < T_STEPS; t++) {
        // ---- x phase: load + MFMA, no h dependence, runs during skew ----
        f32x4 acc0 = {0.f, 0.f, 0.f, 0.f}, acc1 = acc0;
        #pragma unroll
        for (int ks = 0; ks < KX; ks++) {
            int k = ks * 32 + quad * 8;
            int p = k >> 7, f = k & 127;
            const float* sp = x + ((size_t)(rowA * 5 + p) * 256 + t) * 128 + f;
            float4 u0 = *(const float4*)sp;
            float4 u1 = *(const float4*)(sp + 4);
            s16x8 a = pack8(u0, u1);
            s16x8 b0 = *(const s16x8*)(wfl + (((n0    ) * KSTEPS + ks) * 64 + lane) * 8);
            s16x8 b1 = *(const s16x8*)(wfl + (((n0 + 1) * KSTEPS + ks) * 64 + lane) * 8);
            acc0 = __builtin_amdgcn_mfma_f32_16x16x32_bf16(a, b0, acc0, 0, 0, 0);
            acc1 = __builtin_amdgcn_mfma_f32_16x16x32_bf16(a, b1, acc1, 0, 0, 0);
        }

        // ---- group barrier: relaxed spin (NO acquire -> no buffer_inv) ----
        if (tid == 0) {
            while (__hip_atomic_load(mycnt, __ATOMIC_RELAXED,
                                     __HIP_MEMORY_SCOPE_AGENT) < 32 * t)
                __builtin_amdgcn_s_sleep(1);
        }
        __syncthreads();   // gates h loads; also drains x-phase state

        const unsigned short* hsrc = (t & 1) ? hb1 : hb0;
        unsigned short*       hdst = (t & 1) ? hb0 : hb1;

        // ---- h phase: frags via relaxed agent atomics (LLC-fresh) ----
        const unsigned long long* hq =
            (const unsigned long long*)(hsrc + ((size_t)mbg * KH * 64) * 8);
        #pragma unroll
        for (int khs = 0; khs < KH; khs++) {
            union { unsigned long long q[2]; s16x8 v; } a;
            size_t base = ((size_t)khs * 64 + lane) * 2;   // u64 units
            a.q[0] = __hip_atomic_load(hq + base,     __ATOMIC_RELAXED,
                                       __HIP_MEMORY_SCOPE_AGENT);
            a.q[1] = __hip_atomic_load(hq + base + 1, __ATOMIC_RELAXED,
                                       __HIP_MEMORY_SCOPE_AGENT);
            int ks = KX + khs;
            s16x8 b0 = *(const s16x8*)(wfl + (((n0    ) * KSTEPS + ks) * 64 + lane) * 8);
            s16x8 b1 = *(const s16x8*)(wfl + (((n0 + 1) * KSTEPS + ks) * 64 + lane) * 8);
            acc0 = __builtin_amdgcn_mfma_f32_16x16x32_bf16(a.v, b0, acc0, 0, 0, 0);
            acc1 = __builtin_amdgcn_mfma_f32_16x16x32_bf16(a.v, b1, acc1, 0, 0, 0);
        }

        // ---- dump accs to LDS (C/D layout: col=lane&15, row=quad*4+reg) ----
        int colb = n0 * 16 + l16;
        int rowb = mb * 16 + quad * 4;
        #pragma unroll
        for (int r = 0; r < 4; r++) {
            gl[rowb + r][colb]      = acc0[r];
            gl[rowb + r][colb + 16] = acc1[r];
        }
        __syncthreads();

        // ---- epilogue: activations + cell + phased gate, state in regs ----
        float hn2[2];
        #pragma unroll
        for (int r = 0; r < 2; r++) {
            int j_l = j_l0 + r;
            float iv = gl[b_l][j_l]      + bi[r];
            float fv = gl[b_l][16 + j_l] + bff[r];
            float gv = gl[b_l][32 + j_l] + bg[r];
            float ov = gl[b_l][48 + j_l] + bo[r];
            iv = 1.f / (1.f + expf(-iv));
            fv = 1.f / (1.f + expf(-fv));
            gv = tanhf(gv);
            ov = 1.f / (1.f + expf(-ov));
            float ct = fv * creg[r] + iv * gv;
            float ht = ov * tanhf(ct);
            float phi = fmodf((float)t - sj[r], tj[r]);
            phi = (phi < 0.f) ? phi + tj[r] : phi;
            phi /= tj[r];
            float kg = (phi < 0.025f) ? 40.f * phi
                     : ((phi < 0.05f) ? 2.f - 40.f * phi : 0.001f * phi);
            creg[r] = kg * ct + (1.f - kg) * creg[r];
            hreg[r] = kg * ht + (1.f - kg) * hreg[r];
            hn2[r] = hreg[r];
        }
        // publish pair as one u32 write-through (relaxed agent atomic)
        unsigned pv = (unsigned)f2bf(hn2[0]) | ((unsigned)f2bf(hn2[1]) << 16);
        __hip_atomic_store((unsigned*)hdst + pub32, pv, __ATOMIC_RELAXED,
                           __HIP_MEMORY_SCOPE_AGENT);
        if (t == T_STEPS - 1) {
            hplain[(size_t)bG * HID + jG0]     = hn2[0];
            hplain[(size_t)bG * HID + jG0 + 1] = hn2[1];
        }
        __syncthreads();   // drains vmcnt: h publish globally visible at LLC

        // ---- group barrier arrive: relaxed add (no release -> no wbl2) ----
        if (tid == 0)
            __hip_atomic_fetch_add(mycnt, 1, __ATOMIC_RELAXED,
                                   __HIP_MEMORY_SCOPE_AGENT);
    }
}

// ---------------------------------------------------------------------------
// Final FC (512 -> 60) + log_softmax. One wave per batch row.
// ---------------------------------------------------------------------------
__global__ __launch_bounds__(64) void fc_kernel(
    const float* __restrict__ hplain, const float* __restrict__ fcw,
    const float* __restrict__ fcb, float* __restrict__ out)
{
    int b = blockIdx.x, lane = threadIdx.x;
    float logit = -INFINITY;
    if (lane < NCLASS) {
        float s = fcb[lane];
        const float* hp = hplain + (size_t)b * HID;
        #pragma unroll 8
        for (int k = 0; k < HID; k++)
            s += hp[k] * fcw[(size_t)k * NCLASS + lane];
        logit = s;
    }
    float m = logit;
    for (int off = 32; off > 0; off >>= 1)
        m = fmaxf(m, __shfl_xor(m, off, 64));
    float e = (lane < NCLASS) ? expf(logit - m) : 0.f;
    float se = e;
    for (int off = 32; off > 0; off >>= 1)
        se += __shfl_xor(se, off, 64);
    if (lane < NCLASS)
        out[(size_t)b * NCLASS + lane] = logit - m - logf(se);
}

extern "C" void kernel_launch(void* const* d_in, const int* in_sizes, int n_in,
                              void* d_out, int out_size, void* d_ws, size_t ws_size,
                              hipStream_t stream)
{
    const float* x     = (const float*)d_in[0];
    const float* Wx    = (const float*)d_in[1];
    const float* Wh    = (const float*)d_in[2];
    const float* bias  = (const float*)d_in[3];
    const float* tau   = (const float*)d_in[4];
    const float* shift = (const float*)d_in[5];
    const float* fcw   = (const float*)d_in[6];
    const float* fcb   = (const float*)d_in[7];
    float* out = (float*)d_out;
    char* ws = (char*)d_ws;

    int*            cntp   = (int*)ws;
    unsigned short* Wf     = (unsigned short*)(ws + WF_OFF);
    unsigned short* hb0    = (unsigned short*)(ws + HB0_OFF);
    unsigned short* hb1    = (unsigned short*)(ws + HB1_OFF);
    float*          hplain = (float*)(ws + HPL_OFF);

    hipMemsetAsync(ws, 0, 1024, stream);                     // counters
    hipMemsetAsync(ws + HB0_OFF, 0, 262144, stream);         // h0 = 0

    pack_w_kernel<<<dim3(1152), dim3(256), 0, stream>>>(Wx, Wh, Wf);

    plstm_persist<<<dim3(256), dim3(256), 0, stream>>>(
        x, Wf, hb0, hb1, hplain, bias, tau, shift, cntp);

    fc_kernel<<<dim3(256), dim3(64), 0, stream>>>(hplain, fcw, fcb, out);
}